// Round 6
// baseline (5823.579 us; speedup 1.0000x reference)
//
#include <hip/hip_runtime.h>

#define TLEN  512
#define HID   128
#define RSLOT 16   // ring slots/slice (L2-resident live set)

typedef __attribute__((ext_vector_type(8))) short          bf16x8;
typedef __attribute__((ext_vector_type(4))) float          f32x4;
typedef __attribute__((ext_vector_type(2))) float          f32x2;
typedef __attribute__((ext_vector_type(4))) unsigned short u16x4;
typedef unsigned long long u64;

#define LOG2E  1.4426950408889634f
#define LOG2E2 2.8853900817779268f

template<bool B> struct BC { static constexpr bool value = B; };
template<int I>  struct IC { static constexpr int  value = I; };

// RNE (cold paths)
__device__ __forceinline__ unsigned short f2bf(float f) {
    union { float f; unsigned u; } v; v.f = f;
    unsigned r = v.u + 0x7fffu + ((v.u >> 16) & 1u);
    return (unsigned short)(r >> 16);
}
// round-half-up (hot path: h)
__device__ __forceinline__ unsigned short f2bf_fast(float f) {
    union { float f; unsigned u; } v; v.f = f;
    return (unsigned short)((v.u + 0x8000u) >> 16);
}

// packed-lane helpers: exp2/rcp have no packed form -> per-element scalars;
// surrounding arithmetic stays f32x2 so the backend emits v_pk_{fma,mul,add}_f32.
__device__ __forceinline__ f32x2 exp2_2(f32x2 a) {
    f32x2 r; r.x = __builtin_exp2f(a.x); r.y = __builtin_exp2f(a.y); return r;
}
__device__ __forceinline__ f32x2 rcp_2(f32x2 a) {
    f32x2 r; r.x = __builtin_amdgcn_rcpf(a.x); r.y = __builtin_amdgcn_rcpf(a.y); return r;
}

// LDS granule swizzle: phi(g) = g ^ ((g>>4)&3) on 16B granules (R1: bank
// conflicts 7.9M -> 33K). Applied to every hbuf/xbuf access.
// R4 lesson: x-path must stay in LDS (direct ring->reg exposes L2 latency).
// R5 lesson: scheduling micro-surgery is exhausted; the ~700cyc/step stall
// is chain latency that 2 waves/SIMD can't hide -> R6 doubles occupancy by
// fusing TWO 16-batch slices per 1024-thread block (4 waves/SIMD).

// Loads AGENT scope (L1-bypass -> same-XCD L2); stores WORKGROUP scope.
__device__ __forceinline__ int flag_peek(const int* f) {
    return __hip_atomic_load(f, __ATOMIC_RELAXED, __HIP_MEMORY_SCOPE_AGENT);
}
__device__ __forceinline__ int flag_spin(const int* f, int v) {
    int x = flag_peek(f);
    while (x < v) { __builtin_amdgcn_s_sleep(1); x = flag_peek(f); }
    return x;
}
__device__ __forceinline__ void flag_pub(int* f, int v) {
    __hip_atomic_store(f, v, __ATOMIC_RELAXED, __HIP_MEMORY_SCOPE_WORKGROUP);
}

// Split-GEMM LSTM layer: gates(t) = xacc(t) + h(t-1)@W_hh.
// One 512-thread SUB-SLICE of a 1024-thread block runs this; tid is the
// sub-slice-local thread id. __syncthreads() inside spans both sub-slices
// (lockstep, symmetric work — stronger sync is still correct).
template<int MODE, bool CONS, bool PROD, bool WFC>
__device__ __forceinline__ void run_layer_p(
    const float* __restrict__ xin,
    const u64* __restrict__ rin, u64* __restrict__ rout,
    const int* pin_flag, int* cout_flag, const int* cin_flag, int* pout_flag,
    const float* __restrict__ wih, const float* __restrict__ whh,
    const float* __restrict__ bih, const float* __restrict__ bhh,
    unsigned short (* __restrict__ hbuf)[2048],
    unsigned short (* __restrict__ xbuf)[2048],
    float* __restrict__ fcred,
    const int tid, const int wave, const int lane,
    const int n16, const int quad, const int bbase)
{
    constexpr int NKTX = MODE ? 4 : 1;    // x K-tiles of 32
    constexpr int DINL = MODE ? 128 : 6;  // real input features

    // ---- weights -> register B fragments (prescaled) ----
    bf16x8 Wfx[4][NKTX], Wfh[4][4];
    f32x4  bbv[4];
#pragma unroll
    for (int g = 0; g < 4; ++g) {
        const float sc = (g == 2) ? LOG2E2 : LOG2E;
        const int row = g * 128 + wave * 16 + n16;
        const float bg = (bih[row] + bhh[row]) * sc;
        f32x4 bi = {bg, bg, bg, bg};
        bbv[g] = bi;
#pragma unroll
        for (int kt = 0; kt < NKTX; ++kt) {
            bf16x8 wv;
#pragma unroll
            for (int j = 0; j < 8; ++j) {
                const int k = kt * 32 + quad * 8 + j;
                wv[j] = (short)f2bf(((k < DINL) ? wih[row * DINL + k] : 0.0f) * sc);
            }
            Wfx[g][kt] = wv;
        }
#pragma unroll
        for (int kt = 0; kt < 4; ++kt) {
            bf16x8 wv;
#pragma unroll
            for (int j = 0; j < 8; ++j) {
                const int k = kt * 32 + quad * 8 + j;
                wv[j] = (short)f2bf(whh[row * HID + k] * sc);
            }
            Wfh[g][kt] = wv;
        }
    }

    // ---- swizzled LDS offsets (loop-invariant) ----
    const int rof  = (lane ^ quad) * 8;                    // A-frag read: +kt*512
    const int j    = wave * 16 + n16;
    const int beta = ((j & 31) >> 3) & 3;
    const int wbase = ((j >> 5) * 64 + ((j & 31) >> 3) * 16 + quad * 4) * 8 + (j & 7);
    int wof[4];
#pragma unroll
    for (int r = 0; r < 4; ++r) wof[r] = wbase + ((r ^ beta) * 8);
    const int uof  = ((((tid >> 1) ^ ((tid >> 5) & 3))) << 3) + (tid & 1) * 4;
    const int xm = tid >> 5, xk = tid & 31;                // MODE0 commit map
    const int eiS = ((xk >> 3) * 16 + (xm ^ (xk >> 3))) * 8 + (xk & 7);

    // ---- prologue ----
    { u16x4 z = {0, 0, 0, 0}; *(u16x4*)&hbuf[0][uof] = z; }   // h(-1)=0
    u64 q0 = 0, q1 = 0, q2 = 0, qn = 0;
    float pfx0 = 0.0f;
    int pend = 0, cpend = 0;
    if constexpr (CONS) {
        // commit entries 0,1 -> xbuf[0],xbuf[1]; queue entries 2..4
        flag_spin(pin_flag, 1);
        *(u64*)&xbuf[0][uof] =
            __hip_atomic_load(rin + tid, __ATOMIC_RELAXED, __HIP_MEMORY_SCOPE_AGENT);
        flag_spin(pin_flag, 2);
        *(u64*)&xbuf[1][uof] =
            __hip_atomic_load(rin + 512 + tid, __ATOMIC_RELAXED, __HIP_MEMORY_SCOPE_AGENT);
        pend = flag_spin(pin_flag, 5);
        q0 = __hip_atomic_load(rin + 2 * 512 + tid, __ATOMIC_RELAXED, __HIP_MEMORY_SCOPE_AGENT);
        q1 = __hip_atomic_load(rin + 3 * 512 + tid, __ATOMIC_RELAXED, __HIP_MEMORY_SCOPE_AGENT);
        q2 = __hip_atomic_load(rin + 4 * 512 + tid, __ATOMIC_RELAXED, __HIP_MEMORY_SCOPE_AGENT);
    } else {
        // commit x(0),x(1); prefetch x(2)
        float v0 = (xk < DINL) ? xin[((bbase + xm) * TLEN + 0) * DINL + xk] : 0.0f;
        float v1 = (xk < DINL) ? xin[((bbase + xm) * TLEN + 1) * DINL + xk] : 0.0f;
        xbuf[0][eiS] = f2bf(v0);
        xbuf[1][eiS] = f2bf(v1);
        if (xk < DINL) pfx0 = xin[((bbase + xm) * TLEN + 2) * DINL + xk];
    }
    if constexpr (PROD) cpend = -(1 << 30);
    __syncthreads();   // xbuf[0..1], hbuf[0] visible

    // xacc(0) = bias + x(0)@Wx  (bias enters as the C-operand of kt=0)
    f32x4 accA[4], accB[4];
#pragma unroll
    for (int kt = 0; kt < NKTX; ++kt) {
        bf16x8 a = *(const bf16x8*)&xbuf[0][rof + kt * 512];
#pragma unroll
        for (int g = 0; g < 4; ++g)
            accA[g] = __builtin_amdgcn_mfma_f32_16x16x32_bf16(
                a, Wfx[g][kt], (kt == 0) ? bbv[g] : accA[g], 0, 0, 0);
    }

    f32x2 cst2[2] = {{0.f, 0.f}, {0.f, 0.f}};
    float hf[4];

    // SH: compute shadow xacc(t+1). CM: commit x(t+2). CUR/RD/WR compile-time.
    auto step = [&](auto SHc, auto CMc, auto CURc, auto RDc, auto WRc,
                    f32x4 (&accC)[4], f32x4 (&accN)[4], int t) {
        constexpr bool SH  = decltype(SHc)::value;
        constexpr bool CM  = decltype(CMc)::value;
        constexpr int  CUR = decltype(CURc)::value;
        constexpr int  NXT = CUR ^ 1;
        constexpr int  RD  = decltype(RDc)::value;
        constexpr int  WR  = decltype(WRc)::value;
        __syncthreads();   // hbuf[CUR], xbuf[RD] ready; all vmem drained

        const unsigned short* __restrict__ hcur = hbuf[CUR];
        const unsigned short* __restrict__ xrd  = xbuf[RD];

        // ---- CRITICAL A-frag loads first after the barrier ----
        bf16x8 ha_[4];
#pragma unroll
        for (int kt = 0; kt < 4; ++kt) ha_[kt] = *(const bf16x8*)&hcur[rof + kt * 512];

        // ---- shadow: ring load entry t+5 ----
        if constexpr (CONS) {
            if (t + 5 < TLEN) {
                if (pend < t + 6) pend = flag_spin(pin_flag, t + 6);   // rare
                qn = __hip_atomic_load(rin + ((t + 5) & (RSLOT - 1)) * 512 + tid,
                                       __ATOMIC_RELAXED, __HIP_MEMORY_SCOPE_AGENT);
                pend = flag_peek(pin_flag);
            }
        }
        // ---- publish progress ----
        if (tid == 0) {
            if constexpr (CONS) if ((t & 3) == 0) flag_pub(cout_flag, t + 5);
            if constexpr (PROD) if (t >= 2)       flag_pub(pout_flag, t - 1);
        }
        // ---- producer: store entry t-1 (h(t-1) in hbuf[CUR]) ----
        if constexpr (PROD) {
            if (t >= 1) {
                const int e = t - 1;
                if ((e & 3) == 0 && e + 4 > RSLOT && cpend < e + 4 - RSLOT)
                    cpend = flag_spin(cin_flag, e + 4 - RSLOT);        // rare
                u64 hv = *(const u64*)&hcur[uof];
                __hip_atomic_store(rout + (e & (RSLOT - 1)) * 512 + tid, hv,
                                   __ATOMIC_RELAXED, __HIP_MEMORY_SCOPE_WORKGROUP);
                if ((e & 3) == 1) cpend = flag_peek(cin_flag);
            }
        }
        // ---- shadow: global x prefetch (MODE0) ----
        float pfx1 = 0.0f;
        if constexpr (!CONS) {
            if (t + 3 < TLEN && xk < DINL)
                pfx1 = xin[((bbase + xm) * TLEN + (t + 3)) * DINL + xk];
        }

        // ---- CRITICAL: gates = xacc(t) + h(t-1)@W_hh ----
#pragma unroll
        for (int kt = 0; kt < 4; ++kt)
#pragma unroll
            for (int g = 0; g < 4; ++g)
                accC[g] = __builtin_amdgcn_mfma_f32_16x16x32_bf16(ha_[kt], Wfh[g][kt], accC[g], 0, 0, 0);

        // ---- shadow xa_ reads below the critical MFMAs (R5) ----
        __builtin_amdgcn_sched_barrier(0);
        bf16x8 xa_[NKTX];
        if constexpr (SH) {
#pragma unroll
            for (int kt = 0; kt < NKTX; ++kt)
                xa_[kt] = *(const bf16x8*)&xrd[rof + kt * 512];
        }

        // ---- SHADOW: xacc(t+1) = bias + x(t+1)@W_ih ----
        if constexpr (SH) {
#pragma unroll
            for (int kt = 0; kt < NKTX; ++kt)
#pragma unroll
                for (int g = 0; g < 4; ++g)
                    accN[g] = __builtin_amdgcn_mfma_f32_16x16x32_bf16(
                        xa_[kt], Wfx[g][kt], (kt == 0) ? bbv[g] : accN[g], 0, 0, 0);
        }

        // ---- cell update: rcp-merged, packed f32 over r-pairs ----
        const f32x2 one = {1.0f, 1.0f};
#pragma unroll
        for (int p = 0; p < 2; ++p) {
            const f32x2 gi = {accC[0][2 * p], accC[0][2 * p + 1]};
            const f32x2 gf = {accC[1][2 * p], accC[1][2 * p + 1]};
            const f32x2 gg = {accC[2][2 * p], accC[2][2 * p + 1]};
            const f32x2 go = {accC[3][2 * p], accC[3][2 * p + 1]};
            const f32x2 A  = exp2_2(-gi);
            const f32x2 Fv = rcp_2(one + exp2_2(-gf));
            const f32x2 E  = exp2_2(-gg);
            const f32x2 D  = exp2_2(-go);
            const f32x2 ig = (one - E) * rcp_2((one + A) * (one + E));
            const f32x2 c  = Fv * cst2[p] + ig;
            cst2[p] = c;
            f32x2 y;
            y.x = __builtin_amdgcn_fmed3f(c.x * LOG2E2, -30.0f, 30.0f);
            y.y = __builtin_amdgcn_fmed3f(c.y * LOG2E2, -30.0f, 30.0f);
            const f32x2 Cn = exp2_2(-y);
            const f32x2 h2 = (one - Cn) * rcp_2((one + D) * (one + Cn));
            if constexpr (WFC) { hf[2 * p] = h2.x; hf[2 * p + 1] = h2.y; }
            hbuf[NXT][wof[2 * p]]     = f2bf_fast(h2.x);
            hbuf[NXT][wof[2 * p + 1]] = f2bf_fast(h2.y);
        }
        if constexpr (WFC) {
            if (t == TLEN - 1)
#pragma unroll
                for (int r = 0; r < 4; ++r)
                    fcred[(quad * 4 + r) * HID + wave * 16 + n16] = hf[r];
        }
        // ---- commit x(t+2) -> xbuf[WR]; shift queue ----
        if constexpr (CM) {
            if constexpr (CONS) {
                *(u64*)&xbuf[WR][uof] = q0;
                q0 = q1; q1 = q2; q2 = qn;
            } else {
                xbuf[WR][eiS] = f2bf(pfx0);
                pfx0 = pfx1;
            }
        }
    };

    // rd(t)=(t+1)%3, wr(t)=(t+2)%3; 510 = 6*85 -> all constants per instance
    for (int t = 0; t < TLEN - 2; t += 6) {
        step(BC<true>{}, BC<true>{}, IC<0>{}, IC<1>{}, IC<2>{}, accA, accB, t);
        step(BC<true>{}, BC<true>{}, IC<1>{}, IC<2>{}, IC<0>{}, accB, accA, t + 1);
        step(BC<true>{}, BC<true>{}, IC<0>{}, IC<0>{}, IC<1>{}, accA, accB, t + 2);
        step(BC<true>{}, BC<true>{}, IC<1>{}, IC<1>{}, IC<2>{}, accB, accA, t + 3);
        step(BC<true>{}, BC<true>{}, IC<0>{}, IC<2>{}, IC<0>{}, accA, accB, t + 4);
        step(BC<true>{}, BC<true>{}, IC<1>{}, IC<0>{}, IC<1>{}, accB, accA, t + 5);
    }
    step(BC<true>{},  BC<false>{}, IC<0>{}, IC<1>{}, IC<2>{}, accA, accB, TLEN - 2);
    step(BC<false>{}, BC<false>{}, IC<1>{}, IC<2>{}, IC<0>{}, accB, accA, TLEN - 1);

    // ---- producer epilogue: flush entry T-1 ----
    if constexpr (PROD) {
        __syncthreads();   // h(T-1) in hbuf[0]; step T-1 stores drained
        if (tid == 0) flag_pub(pout_flag, TLEN - 1);
        {
            flag_spin(cin_flag, TLEN - RSLOT);
            u64 hv = *(const u64*)&hbuf[TLEN & 1][uof];
            __hip_atomic_store(rout + ((TLEN - 1) & (RSLOT - 1)) * 512 + tid, hv,
                               __ATOMIC_RELAXED, __HIP_MEMORY_SCOPE_WORKGROUP);
        }
        __syncthreads();
        if (tid == 0) flag_pub(pout_flag, TLEN);
    }
}

// 1024-thread block = TWO independent 16-batch sub-slices (4 waves/SIMD).
// Sub-slices share __syncthreads (lockstep, symmetric); each keeps its own
// ring/flags/LDS. Doubles per-SIMD issue work to hide the recurrence chain.
extern "C" __global__ __launch_bounds__(1024, 1)
void lstm3_pipe_kernel(const float* __restrict__ xin,
    const float* __restrict__ wih0, const float* __restrict__ whh0,
    const float* __restrict__ bih0, const float* __restrict__ bhh0,
    const float* __restrict__ wih1, const float* __restrict__ whh1,
    const float* __restrict__ bih1, const float* __restrict__ bhh1,
    const float* __restrict__ wih2, const float* __restrict__ whh2,
    const float* __restrict__ bih2, const float* __restrict__ bhh2,
    const float* __restrict__ fcw, const float* __restrict__ fcb,
    float* __restrict__ out,
    int* __restrict__ flags, u64* __restrict__ ring0, u64* __restrict__ ring1)
{
    __shared__ unsigned short hbuf[2][2][2048];   // 16 KB (per-sub double buf)
    __shared__ unsigned short xbuf[2][3][2048];   // 24 KB
    __shared__ float fcred[2][16 * HID];          // 16 KB

    const int tid   = threadIdx.x;
    const int sub   = tid >> 9;          // sub-slice 0/1
    const int stid  = tid & 511;         // sub-slice-local thread id
    const int wave  = stid >> 6;
    const int lane  = stid & 63;
    const int n16   = lane & 15;
    const int quad  = lane >> 4;

    // bid = ((ssl>>3)*3 + layer)*8 + (ssl&7): all 3 stages of super-slice ssl
    // on one XCD; ssl covers slices {2*ssl, 2*ssl+1}.
    const int xcd    = blockIdx.x & 7;
    const int grp    = blockIdx.x >> 3;
    const int layer  = grp % 3;
    const int sgroup = grp / 3;
    const int ssl    = sgroup * 8 + xcd;
    const int slice  = ssl * 2 + sub;
    const int bbase  = slice * 16;

    u64* r0 = ring0 + (size_t)slice * (RSLOT * 512);
    u64* r1 = ring1 + (size_t)slice * (RSLOT * 512);
    int* prod0 = flags + (size_t)(0 * 64 + slice) * 64;
    int* prod1 = flags + (size_t)(1 * 64 + slice) * 64;
    int* cons1 = flags + (size_t)(2 * 64 + slice) * 64;
    int* cons2 = flags + (size_t)(3 * 64 + slice) * 64;

    if (layer == 0) {
        run_layer_p<0, false, true, false>(xin, nullptr, r0,
            nullptr, nullptr, cons1, prod0,
            wih0, whh0, bih0, bhh0, hbuf[sub], xbuf[sub], fcred[sub],
            stid, wave, lane, n16, quad, bbase);
    } else if (layer == 1) {
        run_layer_p<1, true, true, false>(nullptr, r0, r1,
            prod0, cons1, cons2, prod1,
            wih1, whh1, bih1, bhh1, hbuf[sub], xbuf[sub], fcred[sub],
            stid, wave, lane, n16, quad, bbase);
    } else {
        run_layer_p<1, true, false, true>(nullptr, r1, nullptr,
            prod1, cons2, nullptr, nullptr,
            wih2, whh2, bih2, bhh2, hbuf[sub], xbuf[sub], fcred[sub],
            stid, wave, lane, n16, quad, bbase);
        __syncthreads();
        if (stid < 16) {
            float s = 0.0f;
#pragma unroll 8
            for (int jj = 0; jj < HID; ++jj) s += fcw[jj] * fcred[sub][stid * HID + jj];
            out[bbase + stid] = s + fcb[0];
        }
    }
}

extern "C" void kernel_launch(void* const* d_in, const int* in_sizes, int n_in,
                              void* d_out, int out_size, void* d_ws, size_t ws_size,
                              hipStream_t stream) {
    (void)in_sizes; (void)n_in; (void)out_size; (void)ws_size;
    const float* x    = (const float*)d_in[0];
    const float* wih0 = (const float*)d_in[1];
    const float* whh0 = (const float*)d_in[2];
    const float* bih0 = (const float*)d_in[3];
    const float* bhh0 = (const float*)d_in[4];
    const float* wih1 = (const float*)d_in[5];
    const float* whh1 = (const float*)d_in[6];
    const float* bih1 = (const float*)d_in[7];
    const float* bhh1 = (const float*)d_in[8];
    const float* wih2 = (const float*)d_in[9];
    const float* whh2 = (const float*)d_in[10];
    const float* bih2 = (const float*)d_in[11];
    const float* bhh2 = (const float*)d_in[12];
    const float* fcw  = (const float*)d_in[13];
    const float* fcb  = (const float*)d_in[14];
    float* out = (float*)d_out;

    // ws: flags 64 KB (poison-negative = not ready), ring0 4 MB, ring1 4 MB
    int* flags = (int*)d_ws;
    u64* ring0 = (u64*)((char*)d_ws + 65536);
    u64* ring1 = ring0 + (size_t)64 * RSLOT * 512;

    lstm3_pipe_kernel<<<dim3(96), dim3(1024), 0, stream>>>(
        x, wih0, whh0, bih0, bhh0, wih1, whh1, bih1, bhh1,
        wih2, whh2, bih2, bhh2, fcw, fcb, out, flags, ring0, ring1);
}

// Round 7
// 805.459 us; speedup vs baseline: 7.2301x; 7.2301x over previous
//
#include <hip/hip_runtime.h>

#define TLEN  512
#define HID   128
#define RSLOT 16   // ring slots/slice (L2-resident live set)

typedef __attribute__((ext_vector_type(8))) short          bf16x8;
typedef __attribute__((ext_vector_type(4))) float          f32x4;
typedef __attribute__((ext_vector_type(2))) float          f32x2;
typedef __attribute__((ext_vector_type(4))) unsigned short u16x4;
typedef unsigned long long u64;

#define LOG2E  1.4426950408889634f
#define LOG2E2 2.8853900817779268f

template<bool B> struct BC { static constexpr bool value = B; };
template<int I>  struct IC { static constexpr int  value = I; };

// RNE (cold paths)
__device__ __forceinline__ unsigned short f2bf(float f) {
    union { float f; unsigned u; } v; v.f = f;
    unsigned r = v.u + 0x7fffu + ((v.u >> 16) & 1u);
    return (unsigned short)(r >> 16);
}
// round-half-up (hot path: h)
__device__ __forceinline__ unsigned short f2bf_fast(float f) {
    union { float f; unsigned u; } v; v.f = f;
    return (unsigned short)((v.u + 0x8000u) >> 16);
}

// packed-lane helpers: exp2/rcp have no packed form -> per-element scalars;
// surrounding arithmetic stays f32x2 so the backend emits v_pk_{fma,mul,add}_f32.
__device__ __forceinline__ f32x2 exp2_2(f32x2 a) {
    f32x2 r; r.x = __builtin_exp2f(a.x); r.y = __builtin_exp2f(a.y); return r;
}
__device__ __forceinline__ f32x2 rcp_2(f32x2 a) {
    f32x2 r; r.x = __builtin_amdgcn_rcpf(a.x); r.y = __builtin_amdgcn_rcpf(a.y); return r;
}

// LDS granule swizzle: phi(g) = g ^ ((g>>4)&3) on 16B granules (R1: bank
// conflicts 7.9M -> 33K). Applied to every hbuf/xbuf access.
// R4 lesson: x-path must stay in LDS (direct ring->reg exposes L2 latency).
// R6 lesson: occupancy is PINNED at 2 waves/SIMD — gfx950 unified VGPR+AGPR
// budget is 128/wave at 4 waves/SIMD, but register-resident weights need
// ~190; forcing it spills weights to scratch (VGPR 64 + 1.25 GB FETCH).

// Loads AGENT scope (L1-bypass -> same-XCD L2); stores WORKGROUP scope.
__device__ __forceinline__ int flag_peek(const int* f) {
    return __hip_atomic_load(f, __ATOMIC_RELAXED, __HIP_MEMORY_SCOPE_AGENT);
}
__device__ __forceinline__ int flag_spin(const int* f, int v) {
    int x = flag_peek(f);
    while (x < v) { __builtin_amdgcn_s_sleep(1); x = flag_peek(f); }
    return x;
}
__device__ __forceinline__ void flag_pub(int* f, int v) {
    __hip_atomic_store(f, v, __ATOMIC_RELAXED, __HIP_MEMORY_SCOPE_WORKGROUP);
}

// Split-GEMM LSTM layer: gates(t) = xacc(t) + h(t-1)@W_hh.
// Trans budget per f32x2 pair: 10 exp2 + 4 rcp (c-update merged to ONE rcp:
// c = [c_old*t1 + (1+F)(1-E)] * rcp((1+F)*t1), t1=(1+A)(1+E); h-denominator
// merged as before). Critical h-GEMM split-K: kt{0,1}->accC (carries xacc),
// kt{2,3}->accT (zero C), summed at gate extraction — halves the exposed
// MFMA dependency chain.
template<int MODE, bool CONS, bool PROD, bool WFC>
__device__ __forceinline__ void run_layer_p(
    const float* __restrict__ xin,
    const u64* __restrict__ rin, u64* __restrict__ rout,
    const int* pin_flag, int* cout_flag, const int* cin_flag, int* pout_flag,
    const float* __restrict__ wih, const float* __restrict__ whh,
    const float* __restrict__ bih, const float* __restrict__ bhh,
    unsigned short (* __restrict__ hbuf)[2048],
    unsigned short (* __restrict__ xbuf)[2048],
    float* __restrict__ fcred,
    const int tid, const int wave, const int lane,
    const int n16, const int quad, const int bbase)
{
    constexpr int NKTX = MODE ? 4 : 1;    // x K-tiles of 32
    constexpr int DINL = MODE ? 128 : 6;  // real input features

    // ---- weights -> register B fragments (prescaled) ----
    bf16x8 Wfx[4][NKTX], Wfh[4][4];
    f32x4  bbv[4];
#pragma unroll
    for (int g = 0; g < 4; ++g) {
        const float sc = (g == 2) ? LOG2E2 : LOG2E;
        const int row = g * 128 + wave * 16 + n16;
        const float bg = (bih[row] + bhh[row]) * sc;
        f32x4 bi = {bg, bg, bg, bg};
        bbv[g] = bi;
#pragma unroll
        for (int kt = 0; kt < NKTX; ++kt) {
            bf16x8 wv;
#pragma unroll
            for (int j = 0; j < 8; ++j) {
                const int k = kt * 32 + quad * 8 + j;
                wv[j] = (short)f2bf(((k < DINL) ? wih[row * DINL + k] : 0.0f) * sc);
            }
            Wfx[g][kt] = wv;
        }
#pragma unroll
        for (int kt = 0; kt < 4; ++kt) {
            bf16x8 wv;
#pragma unroll
            for (int j = 0; j < 8; ++j) {
                const int k = kt * 32 + quad * 8 + j;
                wv[j] = (short)f2bf(whh[row * HID + k] * sc);
            }
            Wfh[g][kt] = wv;
        }
    }

    // ---- swizzled LDS offsets (loop-invariant) ----
    const int rof  = (lane ^ quad) * 8;                    // A-frag read: +kt*512
    const int j    = wave * 16 + n16;
    const int beta = ((j & 31) >> 3) & 3;
    const int wbase = ((j >> 5) * 64 + ((j & 31) >> 3) * 16 + quad * 4) * 8 + (j & 7);
    int wof[4];
#pragma unroll
    for (int r = 0; r < 4; ++r) wof[r] = wbase + ((r ^ beta) * 8);
    const int uof  = ((((tid >> 1) ^ ((tid >> 5) & 3))) << 3) + (tid & 1) * 4;
    const int xm = tid >> 5, xk = tid & 31;                // MODE0 commit map
    const int eiS = ((xk >> 3) * 16 + (xm ^ (xk >> 3))) * 8 + (xk & 7);

    // ---- prologue ----
    { u16x4 z = {0, 0, 0, 0}; *(u16x4*)&hbuf[0][uof] = z; }   // h(-1)=0
    u64 q0 = 0, q1 = 0, q2 = 0, qn = 0;
    float pfx0 = 0.0f;
    int pend = 0, cpend = 0;
    if constexpr (CONS) {
        // commit entries 0,1 -> xbuf[0],xbuf[1]; queue entries 2..4
        flag_spin(pin_flag, 1);
        *(u64*)&xbuf[0][uof] =
            __hip_atomic_load(rin + tid, __ATOMIC_RELAXED, __HIP_MEMORY_SCOPE_AGENT);
        flag_spin(pin_flag, 2);
        *(u64*)&xbuf[1][uof] =
            __hip_atomic_load(rin + 512 + tid, __ATOMIC_RELAXED, __HIP_MEMORY_SCOPE_AGENT);
        pend = flag_spin(pin_flag, 5);
        q0 = __hip_atomic_load(rin + 2 * 512 + tid, __ATOMIC_RELAXED, __HIP_MEMORY_SCOPE_AGENT);
        q1 = __hip_atomic_load(rin + 3 * 512 + tid, __ATOMIC_RELAXED, __HIP_MEMORY_SCOPE_AGENT);
        q2 = __hip_atomic_load(rin + 4 * 512 + tid, __ATOMIC_RELAXED, __HIP_MEMORY_SCOPE_AGENT);
    } else {
        // commit x(0),x(1); prefetch x(2)
        float v0 = (xk < DINL) ? xin[((bbase + xm) * TLEN + 0) * DINL + xk] : 0.0f;
        float v1 = (xk < DINL) ? xin[((bbase + xm) * TLEN + 1) * DINL + xk] : 0.0f;
        xbuf[0][eiS] = f2bf(v0);
        xbuf[1][eiS] = f2bf(v1);
        if (xk < DINL) pfx0 = xin[((bbase + xm) * TLEN + 2) * DINL + xk];
    }
    if constexpr (PROD) cpend = -(1 << 30);
    __syncthreads();   // xbuf[0..1], hbuf[0] visible

    // xacc(0) = bias + x(0)@Wx  (bias enters as the C-operand of kt=0)
    f32x4 accA[4], accB[4];
#pragma unroll
    for (int kt = 0; kt < NKTX; ++kt) {
        bf16x8 a = *(const bf16x8*)&xbuf[0][rof + kt * 512];
#pragma unroll
        for (int g = 0; g < 4; ++g)
            accA[g] = __builtin_amdgcn_mfma_f32_16x16x32_bf16(
                a, Wfx[g][kt], (kt == 0) ? bbv[g] : accA[g], 0, 0, 0);
    }

    f32x2 cst2[2] = {{0.f, 0.f}, {0.f, 0.f}};
    float hf[4];

    // SH: compute shadow xacc(t+1). CM: commit x(t+2). CUR/RD/WR compile-time.
    auto step = [&](auto SHc, auto CMc, auto CURc, auto RDc, auto WRc,
                    f32x4 (&accC)[4], f32x4 (&accN)[4], int t) {
        constexpr bool SH  = decltype(SHc)::value;
        constexpr bool CM  = decltype(CMc)::value;
        constexpr int  CUR = decltype(CURc)::value;
        constexpr int  NXT = CUR ^ 1;
        constexpr int  RD  = decltype(RDc)::value;
        constexpr int  WR  = decltype(WRc)::value;
        __syncthreads();   // hbuf[CUR], xbuf[RD] ready; all vmem drained

        const unsigned short* __restrict__ hcur = hbuf[CUR];
        const unsigned short* __restrict__ xrd  = xbuf[RD];

        // ---- CRITICAL A-frag loads first after the barrier ----
        bf16x8 ha_[4];
#pragma unroll
        for (int kt = 0; kt < 4; ++kt) ha_[kt] = *(const bf16x8*)&hcur[rof + kt * 512];

        // ---- shadow: ring load entry t+5 ----
        if constexpr (CONS) {
            if (t + 5 < TLEN) {
                if (pend < t + 6) pend = flag_spin(pin_flag, t + 6);   // rare
                qn = __hip_atomic_load(rin + ((t + 5) & (RSLOT - 1)) * 512 + tid,
                                       __ATOMIC_RELAXED, __HIP_MEMORY_SCOPE_AGENT);
                pend = flag_peek(pin_flag);
            }
        }
        // ---- publish progress ----
        if (tid == 0) {
            if constexpr (CONS) if ((t & 3) == 0) flag_pub(cout_flag, t + 5);
            if constexpr (PROD) if (t >= 2)       flag_pub(pout_flag, t - 1);
        }
        // ---- producer: store entry t-1 (h(t-1) in hbuf[CUR]) ----
        if constexpr (PROD) {
            if (t >= 1) {
                const int e = t - 1;
                if ((e & 3) == 0 && e + 4 > RSLOT && cpend < e + 4 - RSLOT)
                    cpend = flag_spin(cin_flag, e + 4 - RSLOT);        // rare
                u64 hv = *(const u64*)&hcur[uof];
                __hip_atomic_store(rout + (e & (RSLOT - 1)) * 512 + tid, hv,
                                   __ATOMIC_RELAXED, __HIP_MEMORY_SCOPE_WORKGROUP);
                if ((e & 3) == 1) cpend = flag_peek(cin_flag);
            }
        }
        // ---- shadow: global x prefetch (MODE0) ----
        float pfx1 = 0.0f;
        if constexpr (!CONS) {
            if (t + 3 < TLEN && xk < DINL)
                pfx1 = xin[((bbase + xm) * TLEN + (t + 3)) * DINL + xk];
        }

        // ---- CRITICAL: gates = xacc(t) + h(t-1)@W_hh, split-K (chain 4->2):
        //      kt{0,1} -> accC (carries xacc), kt{2,3} -> accT (zero C) ----
        f32x4 accT[4];
        const f32x4 zero4 = {0.0f, 0.0f, 0.0f, 0.0f};
#pragma unroll
        for (int kt = 0; kt < 2; ++kt)
#pragma unroll
            for (int g = 0; g < 4; ++g)
                accC[g] = __builtin_amdgcn_mfma_f32_16x16x32_bf16(ha_[kt], Wfh[g][kt], accC[g], 0, 0, 0);
#pragma unroll
        for (int kt = 2; kt < 4; ++kt)
#pragma unroll
            for (int g = 0; g < 4; ++g)
                accT[g] = __builtin_amdgcn_mfma_f32_16x16x32_bf16(
                    ha_[kt], Wfh[g][kt], (kt == 2) ? zero4 : accT[g], 0, 0, 0);

        // ---- shadow xa_ reads below the critical MFMAs (R5) ----
        __builtin_amdgcn_sched_barrier(0);
        bf16x8 xa_[NKTX];
        if constexpr (SH) {
#pragma unroll
            for (int kt = 0; kt < NKTX; ++kt)
                xa_[kt] = *(const bf16x8*)&xrd[rof + kt * 512];
        }

        // ---- SHADOW: xacc(t+1) = bias + x(t+1)@W_ih ----
        if constexpr (SH) {
#pragma unroll
            for (int kt = 0; kt < NKTX; ++kt)
#pragma unroll
                for (int g = 0; g < 4; ++g)
                    accN[g] = __builtin_amdgcn_mfma_f32_16x16x32_bf16(
                        xa_[kt], Wfx[g][kt], (kt == 0) ? bbv[g] : accN[g], 0, 0, 0);
        }

        // ---- cell update: 10 exp2 + 4 rcp per pair, packed f32 ----
        const f32x2 one = {1.0f, 1.0f};
#pragma unroll
        for (int p = 0; p < 2; ++p) {
            const f32x2 gi = {accC[0][2 * p] + accT[0][2 * p], accC[0][2 * p + 1] + accT[0][2 * p + 1]};
            const f32x2 gf = {accC[1][2 * p] + accT[1][2 * p], accC[1][2 * p + 1] + accT[1][2 * p + 1]};
            const f32x2 gg = {accC[2][2 * p] + accT[2][2 * p], accC[2][2 * p + 1] + accT[2][2 * p + 1]};
            const f32x2 go = {accC[3][2 * p] + accT[3][2 * p], accC[3][2 * p + 1] + accT[3][2 * p + 1]};
            const f32x2 A  = exp2_2(-gi);
            const f32x2 F  = exp2_2(-gf);
            const f32x2 E  = exp2_2(-gg);
            const f32x2 D  = exp2_2(-go);
            // c = [c_old*t1 + (1+F)(1-E)] / [(1+F)*t1],  t1 = (1+A)(1+E)
            const f32x2 t1  = (one + A) * (one + E);
            const f32x2 oF  = one + F;
            const f32x2 num = cst2[p] * t1 + oF * (one - E);
            const f32x2 c   = num * rcp_2(oF * t1);
            cst2[p] = c;
            f32x2 y;
            y.x = __builtin_amdgcn_fmed3f(c.x * LOG2E2, -30.0f, 30.0f);
            y.y = __builtin_amdgcn_fmed3f(c.y * LOG2E2, -30.0f, 30.0f);
            const f32x2 Cn = exp2_2(-y);
            const f32x2 h2 = (one - Cn) * rcp_2((one + D) * (one + Cn));
            if constexpr (WFC) { hf[2 * p] = h2.x; hf[2 * p + 1] = h2.y; }
            hbuf[NXT][wof[2 * p]]     = f2bf_fast(h2.x);
            hbuf[NXT][wof[2 * p + 1]] = f2bf_fast(h2.y);
        }
        if constexpr (WFC) {
            if (t == TLEN - 1)
#pragma unroll
                for (int r = 0; r < 4; ++r)
                    fcred[(quad * 4 + r) * HID + wave * 16 + n16] = hf[r];
        }
        // ---- commit x(t+2) -> xbuf[WR]; shift queue ----
        if constexpr (CM) {
            if constexpr (CONS) {
                *(u64*)&xbuf[WR][uof] = q0;
                q0 = q1; q1 = q2; q2 = qn;
            } else {
                xbuf[WR][eiS] = f2bf(pfx0);
                pfx0 = pfx1;
            }
        }
    };

    // rd(t)=(t+1)%3, wr(t)=(t+2)%3; 510 = 6*85 -> all constants per instance
    for (int t = 0; t < TLEN - 2; t += 6) {
        step(BC<true>{}, BC<true>{}, IC<0>{}, IC<1>{}, IC<2>{}, accA, accB, t);
        step(BC<true>{}, BC<true>{}, IC<1>{}, IC<2>{}, IC<0>{}, accB, accA, t + 1);
        step(BC<true>{}, BC<true>{}, IC<0>{}, IC<0>{}, IC<1>{}, accA, accB, t + 2);
        step(BC<true>{}, BC<true>{}, IC<1>{}, IC<1>{}, IC<2>{}, accB, accA, t + 3);
        step(BC<true>{}, BC<true>{}, IC<0>{}, IC<2>{}, IC<0>{}, accA, accB, t + 4);
        step(BC<true>{}, BC<true>{}, IC<1>{}, IC<0>{}, IC<1>{}, accB, accA, t + 5);
    }
    step(BC<true>{},  BC<false>{}, IC<0>{}, IC<1>{}, IC<2>{}, accA, accB, TLEN - 2);
    step(BC<false>{}, BC<false>{}, IC<1>{}, IC<2>{}, IC<0>{}, accB, accA, TLEN - 1);

    // ---- producer epilogue: flush entry T-1 ----
    if constexpr (PROD) {
        __syncthreads();   // h(T-1) in hbuf[0]; step T-1 stores drained
        if (tid == 0) flag_pub(pout_flag, TLEN - 1);
        {
            flag_spin(cin_flag, TLEN - RSLOT);
            u64 hv = *(const u64*)&hbuf[TLEN & 1][uof];
            __hip_atomic_store(rout + ((TLEN - 1) & (RSLOT - 1)) * 512 + tid, hv,
                               __ATOMIC_RELAXED, __HIP_MEMORY_SCOPE_WORKGROUP);
        }
        __syncthreads();
        if (tid == 0) flag_pub(pout_flag, TLEN);
    }
}

extern "C" __global__ __launch_bounds__(512, 1)
void lstm3_pipe_kernel(const float* __restrict__ xin,
    const float* __restrict__ wih0, const float* __restrict__ whh0,
    const float* __restrict__ bih0, const float* __restrict__ bhh0,
    const float* __restrict__ wih1, const float* __restrict__ whh1,
    const float* __restrict__ bih1, const float* __restrict__ bhh1,
    const float* __restrict__ wih2, const float* __restrict__ whh2,
    const float* __restrict__ bih2, const float* __restrict__ bhh2,
    const float* __restrict__ fcw, const float* __restrict__ fcb,
    float* __restrict__ out,
    int* __restrict__ flags, u64* __restrict__ ring0, u64* __restrict__ ring1)
{
    __shared__ unsigned short hbuf[2][2048];   // 8 KB
    __shared__ unsigned short xbuf[3][2048];   // 12 KB (MODE0 uses 512/slot)
    __shared__ float fcred[16 * HID];          // 8 KB

    const int tid   = threadIdx.x;
    const int wave  = tid >> 6;
    const int lane  = tid & 63;
    const int n16   = lane & 15;
    const int quad  = lane >> 4;

    // bid = ((s>>3)*3 + layer)*8 + (s&7): all 3 stages of slice s on one XCD
    const int xcd    = blockIdx.x & 7;
    const int grp    = blockIdx.x >> 3;
    const int layer  = grp % 3;
    const int sgroup = grp / 3;
    const int slice  = sgroup * 8 + xcd;
    const int bbase  = slice * 16;

    u64* r0 = ring0 + (size_t)slice * (RSLOT * 512);
    u64* r1 = ring1 + (size_t)slice * (RSLOT * 512);
    int* prod0 = flags + (size_t)(0 * 64 + slice) * 64;
    int* prod1 = flags + (size_t)(1 * 64 + slice) * 64;
    int* cons1 = flags + (size_t)(2 * 64 + slice) * 64;
    int* cons2 = flags + (size_t)(3 * 64 + slice) * 64;

    if (layer == 0) {
        run_layer_p<0, false, true, false>(xin, nullptr, r0,
            nullptr, nullptr, cons1, prod0,
            wih0, whh0, bih0, bhh0, hbuf, xbuf, fcred, tid, wave, lane, n16, quad, bbase);
    } else if (layer == 1) {
        run_layer_p<1, true, true, false>(nullptr, r0, r1,
            prod0, cons1, cons2, prod1,
            wih1, whh1, bih1, bhh1, hbuf, xbuf, fcred, tid, wave, lane, n16, quad, bbase);
    } else {
        run_layer_p<1, true, false, true>(nullptr, r1, nullptr,
            prod1, cons2, nullptr, nullptr,
            wih2, whh2, bih2, bhh2, hbuf, xbuf, fcred, tid, wave, lane, n16, quad, bbase);
        __syncthreads();
        if (tid < 16) {
            float s = 0.0f;
#pragma unroll 8
            for (int jj = 0; jj < HID; ++jj) s += fcw[jj] * fcred[tid * HID + jj];
            out[bbase + tid] = s + fcb[0];
        }
    }
}

extern "C" void kernel_launch(void* const* d_in, const int* in_sizes, int n_in,
                              void* d_out, int out_size, void* d_ws, size_t ws_size,
                              hipStream_t stream) {
    (void)in_sizes; (void)n_in; (void)out_size; (void)ws_size;
    const float* x    = (const float*)d_in[0];
    const float* wih0 = (const float*)d_in[1];
    const float* whh0 = (const float*)d_in[2];
    const float* bih0 = (const float*)d_in[3];
    const float* bhh0 = (const float*)d_in[4];
    const float* wih1 = (const float*)d_in[5];
    const float* whh1 = (const float*)d_in[6];
    const float* bih1 = (const float*)d_in[7];
    const float* bhh1 = (const float*)d_in[8];
    const float* wih2 = (const float*)d_in[9];
    const float* whh2 = (const float*)d_in[10];
    const float* bih2 = (const float*)d_in[11];
    const float* bhh2 = (const float*)d_in[12];
    const float* fcw  = (const float*)d_in[13];
    const float* fcb  = (const float*)d_in[14];
    float* out = (float*)d_out;

    // ws: flags 64 KB (poison-negative = not ready), ring0 4 MB, ring1 4 MB
    int* flags = (int*)d_ws;
    u64* ring0 = (u64*)((char*)d_ws + 65536);
    u64* ring1 = ring0 + (size_t)64 * RSLOT * 512;

    lstm3_pipe_kernel<<<dim3(192), dim3(512), 0, stream>>>(
        x, wih0, whh0, bih0, bhh0, wih1, whh1, bih1, bhh1,
        wih2, whh2, bih2, bhh2, fcw, fcb, out, flags, ring0, ring1);
}

// Round 8
// 755.181 us; speedup vs baseline: 7.7115x; 1.0666x over previous
//
#include <hip/hip_runtime.h>

#define TLEN  512
#define HID   128
#define RSLOT 16   // ring slots/slice (L2-resident live set)

typedef __attribute__((ext_vector_type(8))) short          bf16x8;
typedef __attribute__((ext_vector_type(4))) float          f32x4;
typedef __attribute__((ext_vector_type(2))) float          f32x2;
typedef __attribute__((ext_vector_type(4))) unsigned short u16x4;
typedef unsigned long long u64;

#define LOG2E  1.4426950408889634f
#define LOG2E2 2.8853900817779268f

template<bool B> struct BC { static constexpr bool value = B; };
template<int I>  struct IC { static constexpr int  value = I; };

// RNE (cold paths)
__device__ __forceinline__ unsigned short f2bf(float f) {
    union { float f; unsigned u; } v; v.f = f;
    unsigned r = v.u + 0x7fffu + ((v.u >> 16) & 1u);
    return (unsigned short)(r >> 16);
}
// round-half-up (hot path: h)
__device__ __forceinline__ unsigned short f2bf_fast(float f) {
    union { float f; unsigned u; } v; v.f = f;
    return (unsigned short)((v.u + 0x8000u) >> 16);
}

// packed-lane helpers: exp2/rcp have no packed form -> per-element scalars;
// surrounding arithmetic stays f32x2 so the backend emits v_pk_{fma,mul,add}_f32.
__device__ __forceinline__ f32x2 exp2_2(f32x2 a) {
    f32x2 r; r.x = __builtin_exp2f(a.x); r.y = __builtin_exp2f(a.y); return r;
}
__device__ __forceinline__ f32x2 rcp_2(f32x2 a) {
    f32x2 r; r.x = __builtin_amdgcn_rcpf(a.x); r.y = __builtin_amdgcn_rcpf(a.y); return r;
}

// LDS granule swizzle: phi(g) = g ^ ((g>>4)&3) on 16B granules (R1: bank
// conflicts 7.9M -> 33K). Applied to every hbuf/xbuf access.
// R4 lesson: x-path must stay in LDS (direct ring->reg exposes L2 latency).
// R6 lesson: occupancy is PINNED at 2 waves/SIMD (unified VGPR+AGPR file;
// register-resident weights need ~190 regs; 4 waves/SIMD -> weight spill).
// R7 lesson: split-K accT hurt (+16 adds/thread, +16 live VGPR); the MFMA
// chain is NOT the critical path — the VALU/trans stream is.

// Loads AGENT scope (L1-bypass -> same-XCD L2); stores WORKGROUP scope.
__device__ __forceinline__ int flag_peek(const int* f) {
    return __hip_atomic_load(f, __ATOMIC_RELAXED, __HIP_MEMORY_SCOPE_AGENT);
}
__device__ __forceinline__ int flag_spin(const int* f, int v) {
    int x = flag_peek(f);
    while (x < v) { __builtin_amdgcn_s_sleep(1); x = flag_peek(f); }
    return x;
}
__device__ __forceinline__ void flag_pub(int* f, int v) {
    __hip_atomic_store(f, v, __ATOMIC_RELAXED, __HIP_MEMORY_SCOPE_WORKGROUP);
}

// Split-GEMM LSTM layer: gates(t) = xacc(t) + h(t-1)@W_hh.
// Trans budget per cell: 5 exp2 + 2 rcp (c-update single-rcp merge:
// c = [c_old*t1 + (1+F)(1-E)] * rcp((1+F)*t1), t1=(1+A)(1+E); h-denominator
// merged as before). Gate magnitudes weight-norm-bounded => exp2 args
// finite; tanh(c) arg fmed3-clamped to +-30 (c carried raw).
template<int MODE, bool CONS, bool PROD, bool WFC>
__device__ __forceinline__ void run_layer_p(
    const float* __restrict__ xin,
    const u64* __restrict__ rin, u64* __restrict__ rout,
    const int* pin_flag, int* cout_flag, const int* cin_flag, int* pout_flag,
    const float* __restrict__ wih, const float* __restrict__ whh,
    const float* __restrict__ bih, const float* __restrict__ bhh,
    unsigned short (* __restrict__ hbuf)[2048],
    unsigned short (* __restrict__ xbuf)[2048],
    float* __restrict__ fcred,
    const int tid, const int wave, const int lane,
    const int n16, const int quad, const int bbase)
{
    constexpr int NKTX = MODE ? 4 : 1;    // x K-tiles of 32
    constexpr int DINL = MODE ? 128 : 6;  // real input features

    // ---- weights -> register B fragments (prescaled) ----
    bf16x8 Wfx[4][NKTX], Wfh[4][4];
    f32x4  bbv[4];
#pragma unroll
    for (int g = 0; g < 4; ++g) {
        const float sc = (g == 2) ? LOG2E2 : LOG2E;
        const int row = g * 128 + wave * 16 + n16;
        const float bg = (bih[row] + bhh[row]) * sc;
        f32x4 bi = {bg, bg, bg, bg};
        bbv[g] = bi;
#pragma unroll
        for (int kt = 0; kt < NKTX; ++kt) {
            bf16x8 wv;
#pragma unroll
            for (int j = 0; j < 8; ++j) {
                const int k = kt * 32 + quad * 8 + j;
                wv[j] = (short)f2bf(((k < DINL) ? wih[row * DINL + k] : 0.0f) * sc);
            }
            Wfx[g][kt] = wv;
        }
#pragma unroll
        for (int kt = 0; kt < 4; ++kt) {
            bf16x8 wv;
#pragma unroll
            for (int j = 0; j < 8; ++j) {
                const int k = kt * 32 + quad * 8 + j;
                wv[j] = (short)f2bf(whh[row * HID + k] * sc);
            }
            Wfh[g][kt] = wv;
        }
    }

    // ---- swizzled LDS offsets (loop-invariant) ----
    const int rof  = (lane ^ quad) * 8;                    // A-frag read: +kt*512
    const int j    = wave * 16 + n16;
    const int beta = ((j & 31) >> 3) & 3;
    const int wbase = ((j >> 5) * 64 + ((j & 31) >> 3) * 16 + quad * 4) * 8 + (j & 7);
    int wof[4];
#pragma unroll
    for (int r = 0; r < 4; ++r) wof[r] = wbase + ((r ^ beta) * 8);
    const int uof  = ((((tid >> 1) ^ ((tid >> 5) & 3))) << 3) + (tid & 1) * 4;
    const int xm = tid >> 5, xk = tid & 31;                // MODE0 commit map
    const int eiS = ((xk >> 3) * 16 + (xm ^ (xk >> 3))) * 8 + (xk & 7);

    // ---- prologue ----
    { u16x4 z = {0, 0, 0, 0}; *(u16x4*)&hbuf[0][uof] = z; }   // h(-1)=0
    u64 q0 = 0, q1 = 0, q2 = 0, qn = 0;
    float pfx0 = 0.0f;
    int pend = 0, cpend = 0;
    if constexpr (CONS) {
        // commit entries 0,1 -> xbuf[0],xbuf[1]; queue entries 2..4
        flag_spin(pin_flag, 1);
        *(u64*)&xbuf[0][uof] =
            __hip_atomic_load(rin + tid, __ATOMIC_RELAXED, __HIP_MEMORY_SCOPE_AGENT);
        flag_spin(pin_flag, 2);
        *(u64*)&xbuf[1][uof] =
            __hip_atomic_load(rin + 512 + tid, __ATOMIC_RELAXED, __HIP_MEMORY_SCOPE_AGENT);
        pend = flag_spin(pin_flag, 5);
        q0 = __hip_atomic_load(rin + 2 * 512 + tid, __ATOMIC_RELAXED, __HIP_MEMORY_SCOPE_AGENT);
        q1 = __hip_atomic_load(rin + 3 * 512 + tid, __ATOMIC_RELAXED, __HIP_MEMORY_SCOPE_AGENT);
        q2 = __hip_atomic_load(rin + 4 * 512 + tid, __ATOMIC_RELAXED, __HIP_MEMORY_SCOPE_AGENT);
    } else {
        // commit x(0),x(1); prefetch x(2)
        float v0 = (xk < DINL) ? xin[((bbase + xm) * TLEN + 0) * DINL + xk] : 0.0f;
        float v1 = (xk < DINL) ? xin[((bbase + xm) * TLEN + 1) * DINL + xk] : 0.0f;
        xbuf[0][eiS] = f2bf(v0);
        xbuf[1][eiS] = f2bf(v1);
        if (xk < DINL) pfx0 = xin[((bbase + xm) * TLEN + 2) * DINL + xk];
    }
    if constexpr (PROD) cpend = -(1 << 30);
    __syncthreads();   // xbuf[0..1], hbuf[0] visible

    // xacc(0) = bias + x(0)@Wx  (bias enters as the C-operand of kt=0)
    f32x4 accA[4], accB[4];
#pragma unroll
    for (int kt = 0; kt < NKTX; ++kt) {
        bf16x8 a = *(const bf16x8*)&xbuf[0][rof + kt * 512];
#pragma unroll
        for (int g = 0; g < 4; ++g)
            accA[g] = __builtin_amdgcn_mfma_f32_16x16x32_bf16(
                a, Wfx[g][kt], (kt == 0) ? bbv[g] : accA[g], 0, 0, 0);
    }

    f32x2 cst2[2] = {{0.f, 0.f}, {0.f, 0.f}};
    float hf[4];

    // SH: compute shadow xacc(t+1). CM: commit x(t+2). CUR/RD/WR compile-time.
    auto step = [&](auto SHc, auto CMc, auto CURc, auto RDc, auto WRc,
                    f32x4 (&accC)[4], f32x4 (&accN)[4], int t) {
        constexpr bool SH  = decltype(SHc)::value;
        constexpr bool CM  = decltype(CMc)::value;
        constexpr int  CUR = decltype(CURc)::value;
        constexpr int  NXT = CUR ^ 1;
        constexpr int  RD  = decltype(RDc)::value;
        constexpr int  WR  = decltype(WRc)::value;
        __syncthreads();   // hbuf[CUR], xbuf[RD] ready; all vmem drained

        const unsigned short* __restrict__ hcur = hbuf[CUR];
        const unsigned short* __restrict__ xrd  = xbuf[RD];

        // ---- CRITICAL A-frag loads first after the barrier ----
        bf16x8 ha_[4];
#pragma unroll
        for (int kt = 0; kt < 4; ++kt) ha_[kt] = *(const bf16x8*)&hcur[rof + kt * 512];

        // ---- shadow: ring load entry t+5 ----
        if constexpr (CONS) {
            if (t + 5 < TLEN) {
                if (pend < t + 6) pend = flag_spin(pin_flag, t + 6);   // rare
                qn = __hip_atomic_load(rin + ((t + 5) & (RSLOT - 1)) * 512 + tid,
                                       __ATOMIC_RELAXED, __HIP_MEMORY_SCOPE_AGENT);
                pend = flag_peek(pin_flag);
            }
        }
        // ---- publish progress ----
        if (tid == 0) {
            if constexpr (CONS) if ((t & 3) == 0) flag_pub(cout_flag, t + 5);
            if constexpr (PROD) if (t >= 2)       flag_pub(pout_flag, t - 1);
        }
        // ---- producer: store entry t-1 (h(t-1) in hbuf[CUR]) ----
        if constexpr (PROD) {
            if (t >= 1) {
                const int e = t - 1;
                if ((e & 3) == 0 && e + 4 > RSLOT && cpend < e + 4 - RSLOT)
                    cpend = flag_spin(cin_flag, e + 4 - RSLOT);        // rare
                u64 hv = *(const u64*)&hcur[uof];
                __hip_atomic_store(rout + (e & (RSLOT - 1)) * 512 + tid, hv,
                                   __ATOMIC_RELAXED, __HIP_MEMORY_SCOPE_WORKGROUP);
                if ((e & 3) == 1) cpend = flag_peek(cin_flag);
            }
        }
        // ---- shadow: global x prefetch (MODE0) ----
        float pfx1 = 0.0f;
        if constexpr (!CONS) {
            if (t + 3 < TLEN && xk < DINL)
                pfx1 = xin[((bbase + xm) * TLEN + (t + 3)) * DINL + xk];
        }

        // ---- CRITICAL: gates = xacc(t) + h(t-1)@W_hh ----
#pragma unroll
        for (int kt = 0; kt < 4; ++kt)
#pragma unroll
            for (int g = 0; g < 4; ++g)
                accC[g] = __builtin_amdgcn_mfma_f32_16x16x32_bf16(ha_[kt], Wfh[g][kt], accC[g], 0, 0, 0);

        // ---- shadow xa_ reads below the critical MFMAs (R5) ----
        __builtin_amdgcn_sched_barrier(0);
        bf16x8 xa_[NKTX];
        if constexpr (SH) {
#pragma unroll
            for (int kt = 0; kt < NKTX; ++kt)
                xa_[kt] = *(const bf16x8*)&xrd[rof + kt * 512];
        }

        // ---- SHADOW: xacc(t+1) = bias + x(t+1)@W_ih ----
        if constexpr (SH) {
#pragma unroll
            for (int kt = 0; kt < NKTX; ++kt)
#pragma unroll
                for (int g = 0; g < 4; ++g)
                    accN[g] = __builtin_amdgcn_mfma_f32_16x16x32_bf16(
                        xa_[kt], Wfx[g][kt], (kt == 0) ? bbv[g] : accN[g], 0, 0, 0);
        }

        // ---- cell update: 10 exp2 + 4 rcp per pair, packed f32 ----
        const f32x2 one = {1.0f, 1.0f};
#pragma unroll
        for (int p = 0; p < 2; ++p) {
            const f32x2 gi = {accC[0][2 * p], accC[0][2 * p + 1]};
            const f32x2 gf = {accC[1][2 * p], accC[1][2 * p + 1]};
            const f32x2 gg = {accC[2][2 * p], accC[2][2 * p + 1]};
            const f32x2 go = {accC[3][2 * p], accC[3][2 * p + 1]};
            const f32x2 A  = exp2_2(-gi);
            const f32x2 F  = exp2_2(-gf);
            const f32x2 E  = exp2_2(-gg);
            const f32x2 D  = exp2_2(-go);
            // c = [c_old*t1 + (1+F)(1-E)] / [(1+F)*t1],  t1 = (1+A)(1+E)
            const f32x2 t1  = (one + A) * (one + E);
            const f32x2 oF  = one + F;
            const f32x2 num = cst2[p] * t1 + oF * (one - E);
            const f32x2 c   = num * rcp_2(oF * t1);
            cst2[p] = c;
            f32x2 y;
            y.x = __builtin_amdgcn_fmed3f(c.x * LOG2E2, -30.0f, 30.0f);
            y.y = __builtin_amdgcn_fmed3f(c.y * LOG2E2, -30.0f, 30.0f);
            const f32x2 Cn = exp2_2(-y);
            const f32x2 h2 = (one - Cn) * rcp_2((one + D) * (one + Cn));
            if constexpr (WFC) { hf[2 * p] = h2.x; hf[2 * p + 1] = h2.y; }
            hbuf[NXT][wof[2 * p]]     = f2bf_fast(h2.x);
            hbuf[NXT][wof[2 * p + 1]] = f2bf_fast(h2.y);
        }
        if constexpr (WFC) {
            if (t == TLEN - 1)
#pragma unroll
                for (int r = 0; r < 4; ++r)
                    fcred[(quad * 4 + r) * HID + wave * 16 + n16] = hf[r];
        }
        // ---- commit x(t+2) -> xbuf[WR]; shift queue ----
        if constexpr (CM) {
            if constexpr (CONS) {
                *(u64*)&xbuf[WR][uof] = q0;
                q0 = q1; q1 = q2; q2 = qn;
            } else {
                xbuf[WR][eiS] = f2bf(pfx0);
                pfx0 = pfx1;
            }
        }
    };

    // rd(t)=(t+1)%3, wr(t)=(t+2)%3; 510 = 6*85 -> all constants per instance
    for (int t = 0; t < TLEN - 2; t += 6) {
        step(BC<true>{}, BC<true>{}, IC<0>{}, IC<1>{}, IC<2>{}, accA, accB, t);
        step(BC<true>{}, BC<true>{}, IC<1>{}, IC<2>{}, IC<0>{}, accB, accA, t + 1);
        step(BC<true>{}, BC<true>{}, IC<0>{}, IC<0>{}, IC<1>{}, accA, accB, t + 2);
        step(BC<true>{}, BC<true>{}, IC<1>{}, IC<1>{}, IC<2>{}, accB, accA, t + 3);
        step(BC<true>{}, BC<true>{}, IC<0>{}, IC<2>{}, IC<0>{}, accA, accB, t + 4);
        step(BC<true>{}, BC<true>{}, IC<1>{}, IC<0>{}, IC<1>{}, accB, accA, t + 5);
    }
    step(BC<true>{},  BC<false>{}, IC<0>{}, IC<1>{}, IC<2>{}, accA, accB, TLEN - 2);
    step(BC<false>{}, BC<false>{}, IC<1>{}, IC<2>{}, IC<0>{}, accB, accA, TLEN - 1);

    // ---- producer epilogue: flush entry T-1 ----
    if constexpr (PROD) {
        __syncthreads();   // h(T-1) in hbuf[0]; step T-1 stores drained
        if (tid == 0) flag_pub(pout_flag, TLEN - 1);
        {
            flag_spin(cin_flag, TLEN - RSLOT);
            u64 hv = *(const u64*)&hbuf[TLEN & 1][uof];
            __hip_atomic_store(rout + ((TLEN - 1) & (RSLOT - 1)) * 512 + tid, hv,
                               __ATOMIC_RELAXED, __HIP_MEMORY_SCOPE_WORKGROUP);
        }
        __syncthreads();
        if (tid == 0) flag_pub(pout_flag, TLEN);
    }
}

extern "C" __global__ __launch_bounds__(512, 1)
void lstm3_pipe_kernel(const float* __restrict__ xin,
    const float* __restrict__ wih0, const float* __restrict__ whh0,
    const float* __restrict__ bih0, const float* __restrict__ bhh0,
    const float* __restrict__ wih1, const float* __restrict__ whh1,
    const float* __restrict__ bih1, const float* __restrict__ bhh1,
    const float* __restrict__ wih2, const float* __restrict__ whh2,
    const float* __restrict__ bih2, const float* __restrict__ bhh2,
    const float* __restrict__ fcw, const float* __restrict__ fcb,
    float* __restrict__ out,
    int* __restrict__ flags, u64* __restrict__ ring0, u64* __restrict__ ring1)
{
    __shared__ unsigned short hbuf[2][2048];   // 8 KB
    __shared__ unsigned short xbuf[3][2048];   // 12 KB (MODE0 uses 512/slot)
    __shared__ float fcred[16 * HID];          // 8 KB

    const int tid   = threadIdx.x;
    const int wave  = tid >> 6;
    const int lane  = tid & 63;
    const int n16   = lane & 15;
    const int quad  = lane >> 4;

    // bid = ((s>>3)*3 + layer)*8 + (s&7): all 3 stages of slice s on one XCD
    const int xcd    = blockIdx.x & 7;
    const int grp    = blockIdx.x >> 3;
    const int layer  = grp % 3;
    const int sgroup = grp / 3;
    const int slice  = sgroup * 8 + xcd;
    const int bbase  = slice * 16;

    u64* r0 = ring0 + (size_t)slice * (RSLOT * 512);
    u64* r1 = ring1 + (size_t)slice * (RSLOT * 512);
    int* prod0 = flags + (size_t)(0 * 64 + slice) * 64;
    int* prod1 = flags + (size_t)(1 * 64 + slice) * 64;
    int* cons1 = flags + (size_t)(2 * 64 + slice) * 64;
    int* cons2 = flags + (size_t)(3 * 64 + slice) * 64;

    if (layer == 0) {
        run_layer_p<0, false, true, false>(xin, nullptr, r0,
            nullptr, nullptr, cons1, prod0,
            wih0, whh0, bih0, bhh0, hbuf, xbuf, fcred, tid, wave, lane, n16, quad, bbase);
    } else if (layer == 1) {
        run_layer_p<1, true, true, false>(nullptr, r0, r1,
            prod0, cons1, cons2, prod1,
            wih1, whh1, bih1, bhh1, hbuf, xbuf, fcred, tid, wave, lane, n16, quad, bbase);
    } else {
        run_layer_p<1, true, false, true>(nullptr, r1, nullptr,
            prod1, cons2, nullptr, nullptr,
            wih2, whh2, bih2, bhh2, hbuf, xbuf, fcred, tid, wave, lane, n16, quad, bbase);
        __syncthreads();
        if (tid < 16) {
            float s = 0.0f;
#pragma unroll 8
            for (int jj = 0; jj < HID; ++jj) s += fcw[jj] * fcred[tid * HID + jj];
            out[bbase + tid] = s + fcb[0];
        }
    }
}

extern "C" void kernel_launch(void* const* d_in, const int* in_sizes, int n_in,
                              void* d_out, int out_size, void* d_ws, size_t ws_size,
                              hipStream_t stream) {
    (void)in_sizes; (void)n_in; (void)out_size; (void)ws_size;
    const float* x    = (const float*)d_in[0];
    const float* wih0 = (const float*)d_in[1];
    const float* whh0 = (const float*)d_in[2];
    const float* bih0 = (const float*)d_in[3];
    const float* bhh0 = (const float*)d_in[4];
    const float* wih1 = (const float*)d_in[5];
    const float* whh1 = (const float*)d_in[6];
    const float* bih1 = (const float*)d_in[7];
    const float* bhh1 = (const float*)d_in[8];
    const float* wih2 = (const float*)d_in[9];
    const float* whh2 = (const float*)d_in[10];
    const float* bih2 = (const float*)d_in[11];
    const float* bhh2 = (const float*)d_in[12];
    const float* fcw  = (const float*)d_in[13];
    const float* fcb  = (const float*)d_in[14];
    float* out = (float*)d_out;

    // ws: flags 64 KB (poison-negative = not ready), ring0 4 MB, ring1 4 MB
    int* flags = (int*)d_ws;
    u64* ring0 = (u64*)((char*)d_ws + 65536);
    u64* ring1 = ring0 + (size_t)64 * RSLOT * 512;

    lstm3_pipe_kernel<<<dim3(192), dim3(512), 0, stream>>>(
        x, wih0, whh0, bih0, bhh0, wih1, whh1, bih1, bhh1,
        wih2, whh2, bih2, bhh2, fcw, fcb, out, flags, ring0, ring1);
}